// Round 14
// baseline (114.687 us; speedup 1.0000x reference)
//
#include <hip/hip_runtime.h>
#include <math.h>

#define NN 16384
#define T 236
#define TILES 70   // ceil(16384/236); wrap-tile duplicate outputs are bitwise-identical

typedef float f2 __attribute__((ext_vector_type(2)));

// Genuine packed fp32 FMA (gfx950 VOP3P). acc += x * {w,w}.
// Batch-packed operands -> naturally even-aligned VGPR pairs, no mov overhead.
__device__ __forceinline__ void pkfma(f2& acc, f2 x, float w) {
    f2 ws = {w, w};
    asm("v_pk_fma_f32 %0, %1, %2, %0" : "+v"(acc) : "v"(x), "s"(ws));
}

__device__ __forceinline__ f2 elu2(f2 v) {
    f2 r;
    r.x = fmaxf(v.x, 0.0f) + fminf(__expf(v.x) - 1.0f, 0.0f);
    r.y = fmaxf(v.y, 0.0f) + fminf(__expf(v.y) - 1.0f, 0.0f);
    return r;
}

// ---- setup: composite 9-tap weights cw[6][9] = conv1 ∘ [deriv ; I - box] ----
__global__ void smag_setup(const float* __restrict__ dw,
                           const float* __restrict__ fw,
                           const float* __restrict__ W1,
                           float* __restrict__ cw)
{
    const int t = threadIdx.x;
    if (t < 54) {
        const int c = t / 9;
        const int m = (t % 9) - 4;
        float acc = 0.0f;
        #pragma unroll
        for (int k = 0; k < 5; ++k) {
            int j = m + 4 - k;
            if (j >= 0 && j <= 4) acc += W1[c * 10 + k] * dw[j];
        }
        if (m >= -2 && m <= 2) acc += W1[c * 10 + 5 + (m + 2)];
        #pragma unroll
        for (int i = 0; i < 3; ++i) {
            int k = m + 3 - i;
            if (k >= 0 && k <= 4) acc -= fw[i] * W1[c * 10 + 5 + k];
        }
        cw[t] = acc;
    }
}

__global__ __launch_bounds__(256, 8)
void smag_bp2(const float* __restrict__ x,
              const float* __restrict__ dw,
              const float* __restrict__ cw,    // [6][9] composite
              const float* __restrict__ b1,
              const float* __restrict__ W2, const float* __restrict__ b2,
              const float* __restrict__ W3, const float* __restrict__ b3,
              float* __restrict__ out)
{
    const int tile = (int)(blockIdx.x % TILES);
    const int rp   = (int)(blockIdx.x / TILES);   // row pair
    const int tb   = tile * T;
    const int tid  = threadIdx.x;
    const float* __restrict__ x0 = x + (size_t)(2 * rp) * NN;
    const float* __restrict__ x1 = x0 + NN;
    float* __restrict__ o0 = out + (size_t)(2 * rp) * NN;
    float* __restrict__ o1 = o0 + NN;

    // Interleaved arena: every f2 = {row0, row1} -> all LDS accesses aligned b64
    // (lane stride 8B = 2-way bank aliasing = free).
    __shared__ __align__(16) float sm[4952];
    float* const sxi = sm;          // x  : (pos+10)*2 + r, pos in [-10,T+10)
    float* const sh1 = sm + 512;    // h1 : c*496 + (pos+6)*2 + r
    float* const sh2 = sm + 3488;   // h2 : c*488 + (pos+4)*2 + r
    float* const sy  = sm + 512;    // y  : (pos+2)*2 + r  (aliases dead sh1)

    // ---- stage x interleaved ----
    {
        const int pos = tid - 10;                    // [-10, T+10) : exactly 256
        const int g = (tb + pos + NN) & (NN - 1);
        f2 v = {x0[g], x1[g]};
        *(f2*)(sxi + 2 * tid) = v;
    }
    __syncthreads();

    // ---- S2': h1 = elu(conv9(x,cw)+b1); tap-outer so each X read ONCE ----
    if (tid < T + 12) {
        const int q = tid - 6;
        const float* xb = sxi + (q + 6) * 2;         // pos q-4
        f2 acc[6];
        #pragma unroll
        for (int c = 0; c < 6; ++c) acc[c] = (f2){b1[c], b1[c]};
        #pragma unroll
        for (int m = 0; m < 9; ++m) {
            f2 X = *(const f2*)(xb + 2 * m);
            #pragma unroll
            for (int c = 0; c < 6; ++c) pkfma(acc[c], X, cw[c * 9 + m]);
        }
        #pragma unroll
        for (int c = 0; c < 6; ++c)
            *(f2*)(sh1 + c * 496 + (q + 6) * 2) = elu2(acc[c]);
    }
    __syncthreads();

    // ---- S3: h2 = elu(conv5(h1,W2)+b2); window-value-outer, 30 reads ----
    if (tid < T + 8) {
        const int u = tid - 4;
        f2 a0 = {b2[0], b2[0]};
        f2 a1 = {b2[1], b2[1]};
        f2 a2 = {b2[2], b2[2]};
        #pragma unroll
        for (int ci = 0; ci < 6; ++ci) {
            const float* hb = sh1 + ci * 496 + (u + 4) * 2;   // pos u-2
            #pragma unroll
            for (int k = 0; k < 5; ++k) {
                f2 H = *(const f2*)(hb + 2 * k);
                pkfma(a0, H, W2[0 * 30 + ci * 5 + k]);
                pkfma(a1, H, W2[1 * 30 + ci * 5 + k]);
                pkfma(a2, H, W2[2 * 30 + ci * 5 + k]);
            }
        }
        *(f2*)(sh2 + 0 * 488 + (u + 4) * 2) = elu2(a0);
        *(f2*)(sh2 + 1 * 488 + (u + 4) * 2) = elu2(a1);
        *(f2*)(sh2 + 2 * 488 + (u + 4) * 2) = elu2(a2);
    }
    __syncthreads();

    // ---- S4: y; clip(elu(a),0,1)==clamp(a,0,1); xd recomputed from sxi ----
    const float B3v = b3[0];
    const float d0 = dw[0], d1 = dw[1], d2 = dw[2], d3 = dw[3], d4 = dw[4];
    const float K = 1.41421356237309515f * (float)(2.0/16384.0) * (float)(2.0/16384.0);
    if (tid < T + 4) {
        const int v = tid - 2;
        f2 a = {B3v, B3v};
        f2 xd = {0.0f, 0.0f};
        #pragma unroll
        for (int ci = 0; ci < 3; ++ci) {
            const float* hb = sh2 + ci * 488 + (v + 2) * 2;   // pos v-2
            #pragma unroll
            for (int k = 0; k < 5; ++k)
                pkfma(a, *(const f2*)(hb + 2 * k), W3[ci * 5 + k]);
        }
        {
            const float* xb = sxi + (v + 8) * 2;              // pos v-2
            pkfma(xd, *(const f2*)(xb + 0), d0);
            pkfma(xd, *(const f2*)(xb + 2), d1);
            pkfma(xd, *(const f2*)(xb + 4), d2);
            pkfma(xd, *(const f2*)(xb + 6), d3);
            pkfma(xd, *(const f2*)(xb + 8), d4);
        }
        f2 y;
        {
            float c0 = fminf(fmaxf(a.x, 0.0f), 1.0f);
            float c1 = fminf(fmaxf(a.y, 0.0f), 1.0f);
            y.x = (c0 * c0 * K) * fabsf(xd.x) * xd.x;
            y.y = (c1 * c1 * K) * fabsf(xd.y) * xd.y;
        }
        *(f2*)(sy + (v + 2) * 2) = y;
    }
    __syncthreads();

    // ---- S5: out = conv5(y,dw) ----
    if (tid < T) {
        const int s = tid;
        f2 o = {0.0f, 0.0f};
        const float* yb = sy + s * 2;                         // pos s-2
        pkfma(o, *(const f2*)(yb + 0), d0);
        pkfma(o, *(const f2*)(yb + 2), d1);
        pkfma(o, *(const f2*)(yb + 4), d2);
        pkfma(o, *(const f2*)(yb + 6), d3);
        pkfma(o, *(const f2*)(yb + 8), d4);
        const int g = (tb + s) & (NN - 1);
        o0[g] = o.x;
        o1[g] = o.y;
    }
}

extern "C" void kernel_launch(void* const* d_in, const int* in_sizes, int n_in,
                              void* d_out, int out_size, void* d_ws, size_t ws_size,
                              hipStream_t stream) {
    const float* x  = (const float*)d_in[0];
    const float* dw = (const float*)d_in[1];
    const float* fw = (const float*)d_in[2];
    const float* W1 = (const float*)d_in[3];
    const float* b1 = (const float*)d_in[4];
    const float* W2 = (const float*)d_in[5];
    const float* b2 = (const float*)d_in[6];
    const float* W3 = (const float*)d_in[7];
    const float* b3 = (const float*)d_in[8];
    float* out = (float*)d_out;
    float* cw  = (float*)d_ws;   // 54 floats

    hipLaunchKernelGGL(smag_setup, dim3(1), dim3(64), 0, stream, dw, fw, W1, cw);

    const int B = 1024;
    dim3 grid((B / 2) * TILES);   // 512 row-pairs x 70 tiles = 35840 blocks
    dim3 block(256);
    hipLaunchKernelGGL(smag_bp2, grid, block, 0, stream,
                       x, dw, cw, b1, W2, b2, W3, b3, out);
}

// Round 15
// 103.076 us; speedup vs baseline: 1.1126x; 1.1126x over previous
//
#include <hip/hip_runtime.h>
#include <math.h>

#define NN 16384
#define T 236
#define TILES 70   // ceil(16384/236); wrap-tile duplicate outputs are bitwise-identical

typedef float f2 __attribute__((ext_vector_type(2)));

__device__ __forceinline__ f2 elu2(f2 v) {
    f2 e;
    e.x = __expf(v.x);
    e.y = __expf(v.y);
    const f2 zero = (f2)0.0f;
    return __builtin_elementwise_max(v, zero)
         + __builtin_elementwise_min(e - 1.0f, zero);
}

// ---- setup: composite 9-tap weights cw[6][9] = conv1 ∘ [deriv ; I - box] ----
__global__ void smag_setup(const float* __restrict__ dw,
                           const float* __restrict__ fw,
                           const float* __restrict__ W1,
                           float* __restrict__ cw)
{
    const int t = threadIdx.x;
    if (t < 54) {
        const int c = t / 9;
        const int m = (t % 9) - 4;
        float acc = 0.0f;
        #pragma unroll
        for (int k = 0; k < 5; ++k) {
            int j = m + 4 - k;
            if (j >= 0 && j <= 4) acc += W1[c * 10 + k] * dw[j];
        }
        if (m >= -2 && m <= 2) acc += W1[c * 10 + 5 + (m + 2)];
        #pragma unroll
        for (int i = 0; i < 3; ++i) {
            int k = m + 3 - i;
            if (k >= 0 && k <= 4) acc -= fw[i] * W1[c * 10 + 5 + k];
        }
        cw[t] = acc;
    }
}

__global__ __launch_bounds__(256, 8)
void smag_bc(const float* __restrict__ x,
             const float* __restrict__ dw,
             const float* __restrict__ cw,    // [6][9] composite
             const float* __restrict__ b1,
             const float* __restrict__ W2, const float* __restrict__ b2,
             const float* __restrict__ W3, const float* __restrict__ b3,
             float* __restrict__ out)
{
    const int tile = (int)(blockIdx.x % TILES);
    const int rp   = (int)(blockIdx.x / TILES);   // row pair
    const int tb   = tile * T;
    const int tid  = threadIdx.x;
    const float* __restrict__ x0 = x + (size_t)(2 * rp) * NN;
    const float* __restrict__ x1 = x0 + NN;
    float* __restrict__ o0 = out + (size_t)(2 * rp) * NN;
    float* __restrict__ o1 = o0 + NN;

    // Interleaved arena: every f2 = {row0, row1} -> aligned b64 LDS accesses
    // (lane stride 8B = 2-way bank aliasing = free).  19.8 KB -> 8 blocks/CU.
    __shared__ __align__(16) float sm[4952];
    float* const sxi = sm;          // x  : (pos+10)*2 + r, pos in [-10,T+10)
    float* const sh1 = sm + 512;    // h1 : c*496 + (pos+6)*2 + r
    float* const sh2 = sm + 3488;   // h2 : c*488 + (pos+4)*2 + r
    float* const sy  = sm + 512;    // y  : (pos+2)*2 + r  (aliases dead sh1)

    // ---- stage x interleaved ----
    {
        const int pos = tid - 10;                    // [-10, T+10) : exactly 256
        const int g = (tb + pos + NN) & (NN - 1);
        f2 v = {x0[g], x1[g]};
        *(f2*)(sxi + 2 * tid) = v;
    }
    __syncthreads();

    const float d0 = dw[0], d1 = dw[1], d2 = dw[2], d3 = dw[3], d4 = dw[4];

    // ---- S2': h1 = elu(conv9(x,cw)+b1) at q = tid-6; also xd at v = tid-2 ----
    f2 xd_m;
    if (tid < T + 12) {
        const int q = tid - 6;
        const float* xb = sxi + (q + 6) * 2;         // pos q-4
        f2 acc[6];
        #pragma unroll
        for (int c = 0; c < 6; ++c) acc[c] = (f2){b1[c], b1[c]};
        #pragma unroll
        for (int m = 0; m < 9; ++m) {
            f2 X = *(const f2*)(xb + 2 * m);
            #pragma unroll
            for (int c = 0; c < 6; ++c) acc[c] = acc[c] + X * cw[c * 9 + m];
        }
        #pragma unroll
        for (int c = 0; c < 6; ++c)
            *(f2*)(sh1 + c * 496 + (q + 6) * 2) = elu2(acc[c]);
    }
    if (tid < T + 4) {
        // xd at v = tid-2: window pos v-2..v+2 -> sxi offsets (tid+4..tid+8)*2... 
        // pos p maps to sxi + (p+10)*2 ; p = tid-4 .. tid
        const float* xv = sxi + (tid + 6) * 2;       // pos tid-4
        f2 X0 = *(const f2*)(xv + 0);
        f2 X1 = *(const f2*)(xv + 2);
        f2 X2 = *(const f2*)(xv + 4);
        f2 X3 = *(const f2*)(xv + 6);
        f2 X4 = *(const f2*)(xv + 8);
        xd_m = X0 * d0 + X1 * d1 + X2 * d2 + X3 * d3 + X4 * d4;
    }
    __syncthreads();

    // ---- S3: h2 = elu(conv5(h1,W2)+b2) at u = tid-4; each H read once ----
    if (tid < T + 8) {
        const int u = tid - 4;
        f2 a0 = {b2[0], b2[0]};
        f2 a1 = {b2[1], b2[1]};
        f2 a2 = {b2[2], b2[2]};
        #pragma unroll
        for (int ci = 0; ci < 6; ++ci) {
            const float* hb = sh1 + ci * 496 + (u + 4) * 2;   // pos u-2
            #pragma unroll
            for (int k = 0; k < 5; ++k) {
                f2 H = *(const f2*)(hb + 2 * k);
                a0 = a0 + H * W2[0 * 30 + ci * 5 + k];
                a1 = a1 + H * W2[1 * 30 + ci * 5 + k];
                a2 = a2 + H * W2[2 * 30 + ci * 5 + k];
            }
        }
        *(f2*)(sh2 + 0 * 488 + (u + 4) * 2) = elu2(a0);
        *(f2*)(sh2 + 1 * 488 + (u + 4) * 2) = elu2(a1);
        *(f2*)(sh2 + 2 * 488 + (u + 4) * 2) = elu2(a2);
    }
    __syncthreads();

    // ---- S4: y at v = tid-2; clip(elu(a),0,1)==clamp(a,0,1); K=sqrt2*CUT^2 ----
    const float B3v = b3[0];
    const float K = 1.41421356237309515f * (float)(2.0/16384.0) * (float)(2.0/16384.0);
    if (tid < T + 4) {
        const int v = tid - 2;
        f2 a = {B3v, B3v};
        #pragma unroll
        for (int ci = 0; ci < 3; ++ci) {
            const float* hb = sh2 + ci * 488 + (v + 2) * 2;   // pos v-2
            #pragma unroll
            for (int k = 0; k < 5; ++k)
                a = a + *(const f2*)(hb + 2 * k) * W3[ci * 5 + k];
        }
        const f2 zero = (f2)0.0f, one = (f2)1.0f;
        f2 cs = __builtin_elementwise_min(__builtin_elementwise_max(a, zero), one);
        f2 axd = __builtin_elementwise_abs(xd_m);
        f2 y = (cs * cs) * (axd * xd_m) * K;
        *(f2*)(sy + (v + 2) * 2) = y;
    }
    __syncthreads();

    // ---- S5: out = conv5(y,dw) at s = tid ----
    if (tid < T) {
        const int s = tid;
        const float* yb = sy + s * 2;                         // pos s-2
        f2 Y0 = *(const f2*)(yb + 0);
        f2 Y1 = *(const f2*)(yb + 2);
        f2 Y2 = *(const f2*)(yb + 4);
        f2 Y3 = *(const f2*)(yb + 6);
        f2 Y4 = *(const f2*)(yb + 8);
        f2 o = Y0 * d0 + Y1 * d1 + Y2 * d2 + Y3 * d3 + Y4 * d4;
        const int g = (tb + s) & (NN - 1);
        o0[g] = o.x;
        o1[g] = o.y;
    }
}

extern "C" void kernel_launch(void* const* d_in, const int* in_sizes, int n_in,
                              void* d_out, int out_size, void* d_ws, size_t ws_size,
                              hipStream_t stream) {
    const float* x  = (const float*)d_in[0];
    const float* dw = (const float*)d_in[1];
    const float* fw = (const float*)d_in[2];
    const float* W1 = (const float*)d_in[3];
    const float* b1 = (const float*)d_in[4];
    const float* W2 = (const float*)d_in[5];
    const float* b2 = (const float*)d_in[6];
    const float* W3 = (const float*)d_in[7];
    const float* b3 = (const float*)d_in[8];
    float* out = (float*)d_out;
    float* cw  = (float*)d_ws;   // 54 floats

    hipLaunchKernelGGL(smag_setup, dim3(1), dim3(64), 0, stream, dw, fw, W1, cw);

    const int B = 1024;
    dim3 grid((B / 2) * TILES);   // 512 row-pairs x 70 tiles = 35840 blocks
    dim3 block(256);
    hipLaunchKernelGGL(smag_bc, grid, block, 0, stream,
                       x, dw, cw, b1, W2, b2, W3, b3, out);
}

// Round 16
// 96.633 us; speedup vs baseline: 1.1868x; 1.0667x over previous
//
#include <hip/hip_runtime.h>
#include <math.h>

#define NN 16384
#define T 500
#define TILES 33   // ceil(16384/500); wrap tiles: 0 and 32 only

typedef float f2 __attribute__((ext_vector_type(2)));

__device__ __forceinline__ float elu1(float v) {
    return v > 0.0f ? v : __expf(v) - 1.0f;   // cmp+cndmask form
}
__device__ __forceinline__ f2 elu2(f2 v) {
    f2 r; r.x = elu1(v.x); r.y = elu1(v.y); return r;
}

// ---- setup: composite 9-tap weights cw[6][9] = conv1 ∘ [deriv ; I - box] ----
__global__ void smag_setup(const float* __restrict__ dw,
                           const float* __restrict__ fw,
                           const float* __restrict__ W1,
                           float* __restrict__ cw)
{
    const int t = threadIdx.x;
    if (t < 54) {
        const int c = t / 9;
        const int m = (t % 9) - 4;
        float acc = 0.0f;
        #pragma unroll
        for (int k = 0; k < 5; ++k) {
            int j = m + 4 - k;
            if (j >= 0 && j <= 4) acc += W1[c * 10 + k] * dw[j];
        }
        if (m >= -2 && m <= 2) acc += W1[c * 10 + 5 + (m + 2)];
        #pragma unroll
        for (int i = 0; i < 3; ++i) {
            int k = m + 3 - i;
            if (k >= 0 && k <= 4) acc -= fw[i] * W1[c * 10 + 5 + k];
        }
        cw[t] = acc;
    }
}

__global__ __launch_bounds__(256, 8)
void smag_t6(const float* __restrict__ x,
             const float* __restrict__ dw,
             const float* __restrict__ cw,    // [6][9] composite
             const float* __restrict__ b1,
             const float* __restrict__ W2, const float* __restrict__ b2,
             const float* __restrict__ W3, const float* __restrict__ b3,
             float* __restrict__ out)
{
    const int blk = (int)(blockIdx.x % TILES);
    const int row = (int)(blockIdx.x / TILES);
    const int tb  = blk * T;
    const int tid = threadIdx.x;
    const bool wraps = (blk == 0) | (blk == TILES - 1);   // block-uniform
    const float* __restrict__ xr = x   + (size_t)row * NN;
    float* __restrict__ outr     = out + (size_t)row * NN;

    // Aliased arena: 4608 floats = 18.4 KB -> 8 blocks/CU.
    //   sh1 [0,3072)    live S2..S3   | sy [0,504) live S4..S5 (sh1 dead)
    //   sh2 [3072,4608) live S3..S4
    __shared__ __align__(16) float sm[4608];
    float* const sh1 = sm;          // [6][512] h1 : idx = c*512 + pos + 6, pos in [-6,506)
    float* const sy  = sm;          // y  : idx = pos + 2, pos in [-2,502)
    float* const sh2 = sm + 3072;   // [3][512] h2 : idx = c*512 + pos + 4, pos in [-4,504)

    const float d0 = dw[0], d1 = dw[1], d2 = dw[2], d3 = dw[3], d4 = dw[4];

    // ---- S2': h1 pair at p = 2*tid-6 (exactly 256 pairs); xd at p+4 ----
    f2 xd_m;
    {
        const int p = 2 * tid - 6;
        f2 G[6];
        if (wraps) {
            #pragma unroll
            for (int i = 0; i < 6; ++i) {
                int g = (tb + p - 4 + 2 * i + NN) & (NN - 1);
                G[i] = *(const f2*)(xr + g);
            }
        } else {
            const float* xp = xr + tb + p - 4;   // one base, imm offsets
            #pragma unroll
            for (int i = 0; i < 6; ++i)
                G[i] = *(const f2*)(xp + 2 * i);
        }
        f2 w9[9] = {G[0], {G[0].y, G[1].x}, G[1], {G[1].y, G[2].x}, G[2],
                    {G[2].y, G[3].x}, G[3], {G[3].y, G[4].x}, G[4]};
        #pragma unroll
        for (int c = 0; c < 6; ++c) {
            f2 a = (f2)b1[c];
            #pragma unroll
            for (int m = 0; m < 9; ++m)
                a = a + w9[m] * cw[c * 9 + m];
            *(f2*)(sh1 + c * 512 + p + 6) = elu2(a);
        }
        f2 a12 = {G[3].y, G[4].x};
        f2 a34 = {G[4].y, G[5].x};
        xd_m = G[3] * d0 + a12 * d1 + G[4] * d2 + a34 * d3 + G[5] * d4;
    }
    __syncthreads();

    // ---- S3: h2 pair at q = 2*tid-4 (254 pairs) ----
    if (tid < 254) {
        const int q = 2 * tid - 4;
        f2 acc0 = (f2)b2[0], acc1 = (f2)b2[1], acc2 = (f2)b2[2];
        #pragma unroll
        for (int ci = 0; ci < 6; ++ci) {
            const float* hb = sh1 + ci * 512 + q + 4;   // h1[ci] at q-2
            f2 H0 = *(f2*)(hb);
            f2 H1 = *(f2*)(hb + 2);
            f2 H2 = *(f2*)(hb + 4);
            f2 ha[5] = {H0, {H0.y, H1.x}, H1, {H1.y, H2.x}, H2};
            #pragma unroll
            for (int k = 0; k < 5; ++k) {
                acc0 = acc0 + ha[k] * W2[0 * 30 + ci * 5 + k];
                acc1 = acc1 + ha[k] * W2[1 * 30 + ci * 5 + k];
                acc2 = acc2 + ha[k] * W2[2 * 30 + ci * 5 + k];
            }
        }
        *(f2*)(sh2 + 0 * 512 + q + 4) = elu2(acc0);
        *(f2*)(sh2 + 1 * 512 + q + 4) = elu2(acc1);
        *(f2*)(sh2 + 2 * 512 + q + 4) = elu2(acc2);
    }
    __syncthreads();

    // ---- S4: y pair at q = 2*tid-2 (252 pairs); clip(elu(a),0,1)==clamp(a,0,1) ----
    const float B3v = b3[0];
    const float K = 1.41421356237309515f * (float)(2.0/16384.0) * (float)(2.0/16384.0);
    if (tid < 252) {
        const int q = 2 * tid - 2;
        f2 a = (f2)B3v;
        #pragma unroll
        for (int ci = 0; ci < 3; ++ci) {
            const float* hb = sh2 + ci * 512 + q + 2;   // h2[ci] at q-2
            f2 H0 = *(f2*)(hb);
            f2 H1 = *(f2*)(hb + 2);
            f2 H2 = *(f2*)(hb + 4);
            f2 ha1 = {H0.y, H1.x};
            f2 ha3 = {H1.y, H2.x};
            a = a + H0 * W3[ci * 5 + 0] + ha1 * W3[ci * 5 + 1] + H1 * W3[ci * 5 + 2]
                  + ha3 * W3[ci * 5 + 3] + H2 * W3[ci * 5 + 4];
        }
        f2 cs = __builtin_elementwise_min(__builtin_elementwise_max(a, (f2)0.0f), (f2)1.0f);
        f2 axd = __builtin_elementwise_abs(xd_m);
        f2 y = (cs * cs) * (axd * xd_m) * K;
        *(f2*)(sy + q + 2) = y;
    }
    __syncthreads();

    // ---- S5: out pair at s = 2*tid (250 pairs) ----
    if (tid < 250) {
        const int s = 2 * tid;
        f2 Y0 = *(f2*)(sy + s);          // y[s-2], y[s-1]
        f2 Y1 = *(f2*)(sy + s + 2);      // y[s],   y[s+1]
        f2 Y2 = *(f2*)(sy + s + 4);      // y[s+2], y[s+3]
        f2 a12 = {Y0.y, Y1.x};
        f2 a34 = {Y1.y, Y2.x};
        f2 o = Y0 * d0 + a12 * d1 + Y1 * d2 + a34 * d3 + Y2 * d4;
        if (wraps)
            *(f2*)(outr + ((tb + s) & (NN - 1))) = o;
        else
            *(f2*)(outr + tb + s) = o;
    }
}

extern "C" void kernel_launch(void* const* d_in, const int* in_sizes, int n_in,
                              void* d_out, int out_size, void* d_ws, size_t ws_size,
                              hipStream_t stream) {
    const float* x  = (const float*)d_in[0];
    const float* dw = (const float*)d_in[1];
    const float* fw = (const float*)d_in[2];
    const float* W1 = (const float*)d_in[3];
    const float* b1 = (const float*)d_in[4];
    const float* W2 = (const float*)d_in[5];
    const float* b2 = (const float*)d_in[6];
    const float* W3 = (const float*)d_in[7];
    const float* b3 = (const float*)d_in[8];
    float* out = (float*)d_out;
    float* cw  = (float*)d_ws;   // 54 floats

    hipLaunchKernelGGL(smag_setup, dim3(1), dim3(64), 0, stream, dw, fw, W1, cw);

    const int B = 1024;
    dim3 grid(B * TILES);       // 33792 blocks
    dim3 block(256);
    hipLaunchKernelGGL(smag_t6, grid, block, 0, stream,
                       x, dw, cw, b1, W2, b2, W3, b3, out);
}